// Round 4
// baseline (591.443 us; speedup 1.0000x reference)
//
#include <hip/hip_runtime.h>
#include <math.h>

// Problem constants
#define BB 4
#define CC 64
#define HH 128
#define WW 128
#define GG 8
#define COO 64
#define HWC (HH*WW)

typedef float f32x16 __attribute__((ext_vector_type(16)));
typedef __bf16 bf16x8 __attribute__((ext_vector_type(8)));

__device__ __forceinline__ unsigned short bf16_rn(float f) {
    unsigned int u = __float_as_uint(f);
    unsigned int r = (u + 0x7fffu + ((u >> 16) & 1u)) >> 16;
    return (unsigned short)r;
}
__device__ __forceinline__ float b2f(unsigned short u) {
    return __uint_as_float(((unsigned int)u) << 16);
}

// ---------------------------------------------------------------------------
// NCHW fp32 -> channel-blocked bf16 "c16": out[((b*4+cg)*HWC + pix)*16 + ci].
// Conv B-fragment loads from this layout are fully contiguous (1 KB/wave).
// ---------------------------------------------------------------------------
__global__ __launch_bounds__(256) void to_c16_kernel(const float* __restrict__ in,
                                                     unsigned short* __restrict__ out) {
    __shared__ unsigned short lds[64][66];
    const int b = blockIdx.y;
    const int pix0 = blockIdx.x * 64;
    const int t = threadIdx.x;
    {
        const int p = t & 63, q = t >> 6;
#pragma unroll
        for (int i = 0; i < 16; i++) {
            int c = i * 4 + q;
            lds[c][p] = bf16_rn(in[((size_t)b * 64 + c) * HWC + pix0 + p]);
        }
    }
    __syncthreads();
    {
        const int pl = t & 63, cg = t >> 6;
        unsigned int u[8];
#pragma unroll
        for (int j = 0; j < 8; j++) {
            unsigned int lo = lds[cg * 16 + 2 * j][pl];
            unsigned int hi = lds[cg * 16 + 2 * j + 1][pl];
            u[j] = lo | (hi << 16);
        }
        unsigned int* dst = (unsigned int*)(out + ((size_t)(b * 4 + cg) * HWC + pix0 + pl) * 16);
        *(uint4*)dst = make_uint4(u[0], u[1], u[2], u[3]);
        *(uint4*)(dst + 4) = make_uint4(u[4], u[5], u[6], u[7]);
    }
}

// ---------------------------------------------------------------------------
// Interleave x & share (NCHW fp32) into NCHW uint32: lo16=bf16(x),
// hi16=bf16(share). One 4B read serves BOTH deform convs.
// ---------------------------------------------------------------------------
__global__ __launch_bounds__(256) void pack_xs_kernel(const float* __restrict__ x,
                                                      const float* __restrict__ s,
                                                      unsigned int* __restrict__ xs, int n) {
    int i = blockIdx.x * 256 + threadIdx.x;
    if (i < n) {
        xs[i] = (unsigned int)bf16_rn(x[i]) | ((unsigned int)bf16_rn(s[i]) << 16);
    }
}

// ---------------------------------------------------------------------------
// Pack conv weights [Cout][CinTot][3][3] fp32 into MFMA A-fragment order:
// wp[((seg*9+kk)*4+cg)][co_pad][16c] bf16, zero-padded for co >= Cout.
// ---------------------------------------------------------------------------
__global__ void pack_w_kernel(const float* __restrict__ w, unsigned short* __restrict__ wp,
                              int Cout, int COP, int CinTot, int n) {
    int idx = blockIdx.x * 256 + threadIdx.x;
    if (idx >= n) return;
    int i  = idx & 15;
    int co = (idx >> 4) % COP;
    int t  = idx / (16 * COP);       // t = (seg*9+kk)*4+cg
    int cg = t & 3;
    int kk = (t >> 2) % 9;
    int seg = t / 36;
    int cin = seg * 64 + cg * 16 + i;
    float v = (co < Cout) ? w[((size_t)co * CinTot + cin) * 9 + kk] : 0.f;
    wp[idx] = bf16_rn(v);
}

// ---------------------------------------------------------------------------
// Implicit-GEMM 3x3 conv via mfma_f32_32x32x16_bf16, inputs in c16 layout.
// Wave tile: 32 Cout x 128 pix (one image row). Block = 4 waves = 4 rows.
// grid = (B*H/4, COP/32).
// out_mode: 2 = NCHW bf16, 3 = c16 bf16
// act: 1 leaky(0.1), 2 sigmoid, 3 sigmoid for co>=144
// ---------------------------------------------------------------------------
template<int NSEG>
__global__ __launch_bounds__(256, 4) void conv_mfma_kernel(
    const unsigned short* __restrict__ in0,
    const unsigned short* __restrict__ in1,
    const unsigned short* __restrict__ wp,
    const float* __restrict__ bias,
    void* __restrict__ out,
    int Cout, int COP, int out_mode, int act)
{
    const int lane = threadIdx.x & 63;
    const int wid  = threadIdx.x >> 6;
    const int l31  = lane & 31;
    const int half = lane >> 5;
    const int b    = blockIdx.x >> 5;
    const int r    = ((blockIdx.x & 31) << 2) + wid;   // image row, wave-uniform
    const int co0  = blockIdx.y * 32;

    f32x16 acc[4];
#pragma unroll
    for (int nt = 0; nt < 4; nt++)
#pragma unroll
        for (int rg = 0; rg < 16; rg++) acc[nt][rg] = 0.f;

    bf16x8 bz;
#pragma unroll
    for (int i = 0; i < 8; i++) bz[i] = (__bf16)0.f;

#pragma unroll
    for (int seg = 0; seg < NSEG; seg++) {
        const unsigned short* in = seg ? in1 : in0;
        const unsigned short* inb = in + (size_t)b * 4 * HWC * 16;
        for (int kk = 0; kk < 9; kk++) {
            const int rr = r + kk / 3 - 1;
            if ((unsigned)rr < (unsigned)HH) {
                const int dxo = kk % 3 - 1;
#pragma unroll
                for (int cg = 0; cg < 4; cg++) {
                    bf16x8 afrag = *(const bf16x8*)(wp +
                        ((size_t)(((seg * 9 + kk) * 4 + cg) * COP + co0 + l31) * 16 + half * 8));
                    const size_t plane = ((size_t)cg * HWC + (size_t)rr * WW) * 16;
#pragma unroll
                    for (int nt = 0; nt < 4; nt++) {
                        const int cc = nt * 32 + l31 + dxo;
                        bf16x8 bfrag = bz;
                        if ((unsigned)cc < (unsigned)WW)
                            bfrag = *(const bf16x8*)(inb + plane + (size_t)cc * 16 + half * 8);
                        acc[nt] = __builtin_amdgcn_mfma_f32_32x32x16_bf16(afrag, bfrag, acc[nt], 0, 0, 0);
                    }
                }
            }
        }
    }

    // Epilogue: D layout col(pix)=lane&31, row(co)=(rg&3)+8*(rg>>2)+4*half
#pragma unroll
    for (int nt = 0; nt < 4; nt++) {
#pragma unroll
        for (int rg = 0; rg < 16; rg++) {
            const int row = (rg & 3) + 8 * (rg >> 2) + 4 * half;
            const int co = co0 + row;
            if (co < Cout) {
                float v = acc[nt][rg] + bias[co];
                if (act == 1)      v = (v >= 0.f) ? v : 0.1f * v;
                else if (act == 2) v = 1.f / (1.f + __expf(-v));
                else if (act == 3 && co >= 144) v = 1.f / (1.f + __expf(-v));
                const int pix = r * WW + nt * 32 + l31;
                if (out_mode == 2)
                    ((unsigned short*)out)[((size_t)b * Cout + co) * HWC + pix] = bf16_rn(v);
                else // c16
                    ((unsigned short*)out)[((size_t)(b * 4 + (co >> 4)) * HWC + pix) * 16 + (co & 15)] = bf16_rn(v);
            }
        }
    }
}

// ---------------------------------------------------------------------------
// Fused dual modulated deformable conv with LDS window staging.
// Block = one (b,g) x 16x16 pixel tile. Stage clamped 24x24 window (halo 4)
// of 8 interleaved channels (u32 = bf16 x | bf16 share) into LDS; all
// bilinear gathers become ds_read_b32. Offsets beyond the halo (≈8 sigma)
// take a rare global fallback path. Fully unrolled (no dynamic indexing ->
// no scratch). g from blockIdx -> w_dc loads are scalar.
// ---------------------------------------------------------------------------
__global__ __launch_bounds__(256, 4) void deform_fused_kernel(
    const unsigned int* __restrict__ xs,
    const unsigned short* __restrict__ om, const unsigned short* __restrict__ em,
    const float* __restrict__ wdc, const float* __restrict__ bdc,
    float* __restrict__ outx, float* __restrict__ outs)
{
    __shared__ unsigned int lds[8][24][25];   // 19200 B

    const int bg = blockIdx.x >> 6;           // b*8+g
    const int b = bg >> 3, g = bg & 7;
    const int tile = blockIdx.x & 63;
    const int r0 = (tile >> 3) << 4;
    const int c0 = (tile & 7) << 4;
    const int tx = threadIdx.x & 15, ty = threadIdx.x >> 4;
    const int h = r0 + ty, w = c0 + tx;
    const int wr0 = r0 - 4, wc0 = c0 - 4;

    const unsigned int* xsb = xs + ((size_t)b * 64 + g * 8) * HWC;

    // Stage 8 channels x 24x24 clamped window
#pragma unroll
    for (int i = 0; i < 18; i++) {
        unsigned int slot = (unsigned int)threadIdx.x + i * 256u;   // 0..4607
        unsigned int sx = slot % 24u;
        unsigned int t2 = slot / 24u;
        unsigned int sy = t2 % 24u;
        unsigned int c  = t2 / 24u;
        int iy = min(max(wr0 + (int)sy, 0), HH - 1);
        int ix = min(max(wc0 + (int)sx, 0), WW - 1);
        lds[c][sy][sx] = xsb[(size_t)c * HWC + iy * WW + ix];
    }

    // Hoist offset/mask loads (independent of staging)
    const int pix = h * WW + w;
    const unsigned short* omb = om + (size_t)b * 216 * HWC + pix;
    const unsigned short* emb = em + (size_t)b * 72 * HWC + pix;
    float dys[9], dxs[9], m1s[9], m2s[9];
#pragma unroll
    for (int kk = 0; kk < 9; kk++) {
        dys[kk] = b2f(omb[(size_t)(g * 18 + kk * 2) * HWC]);
        dxs[kk] = b2f(omb[(size_t)(g * 18 + kk * 2 + 1) * HWC]);
        m1s[kk] = b2f(omb[(size_t)(144 + g * 9 + kk) * HWC]);
        m2s[kk] = b2f(emb[(size_t)(g * 9 + kk) * HWC]);
    }

    __syncthreads();

    float accx[8], accs[8];
#pragma unroll
    for (int o = 0; o < 8; o++) { accx[o] = 0.f; accs[o] = 0.f; }

    const unsigned int* lp = &lds[0][0][0];

#pragma unroll
    for (int kk = 0; kk < 9; kk++) {
        const float py = (float)(h - 1 + kk / 3) + dys[kk];
        const float px = (float)(w - 1 + kk % 3) + dxs[kk];
        const float y0f = floorf(py), x0f = floorf(px);
        const float ly = py - y0f, lx = px - x0f;
        const int y0 = (int)y0f, x0 = (int)x0f;
        const int y1 = y0 + 1, x1 = x0 + 1;
        const bool vy0 = (y0 >= 0) && (y0 < HH), vy1 = (y1 >= 0) && (y1 < HH);
        const bool vx0 = (x0 >= 0) && (x0 < WW), vx1 = (x1 >= 0) && (x1 < WW);
        float w00 = (1.f - ly) * (1.f - lx); if (!(vy0 && vx0)) w00 = 0.f;
        float w01 = (1.f - ly) * lx;         if (!(vy0 && vx1)) w01 = 0.f;
        float w10 = ly * (1.f - lx);         if (!(vy1 && vx0)) w10 = 0.f;
        float w11 = ly * lx;                 if (!(vy1 && vx1)) w11 = 0.f;
        const int cy0 = min(max(y0, 0), HH - 1), cy1 = min(max(y1, 0), HH - 1);
        const int cx0 = min(max(x0, 0), WW - 1), cx1 = min(max(x1, 0), WW - 1);
        const float m1 = m1s[kk], m2 = m2s[kk];

        const int sy0 = cy0 - wr0, sy1 = cy1 - wr0;
        const int sx0 = cx0 - wc0, sx1 = cx1 - wc0;
        const bool inw = (sy0 >= 0) && (sy1 < 24) && (sx0 >= 0) && (sx1 < 24);

        unsigned int u00[8], u01[8], u10[8], u11[8];
        if (inw) {
            const int a00 = sy0 * 25 + sx0, a01 = sy0 * 25 + sx1;
            const int a10 = sy1 * 25 + sx0, a11 = sy1 * 25 + sx1;
#pragma unroll
            for (int c = 0; c < 8; c++) {
                u00[c] = lp[c * 600 + a00]; u01[c] = lp[c * 600 + a01];
                u10[c] = lp[c * 600 + a10]; u11[c] = lp[c * 600 + a11];
            }
        } else {
            const int i00 = cy0 * WW + cx0, i01 = cy0 * WW + cx1;
            const int i10 = cy1 * WW + cx0, i11 = cy1 * WW + cx1;
#pragma unroll
            for (int c = 0; c < 8; c++) {
                const unsigned int* xc = xsb + (size_t)c * HWC;
                u00[c] = xc[i00]; u01[c] = xc[i01];
                u10[c] = xc[i10]; u11[c] = xc[i11];
            }
        }

#pragma unroll
        for (int c = 0; c < 8; c++) {
            float x00 = __uint_as_float(u00[c] << 16), s00 = __uint_as_float(u00[c] & 0xffff0000u);
            float x01 = __uint_as_float(u01[c] << 16), s01 = __uint_as_float(u01[c] & 0xffff0000u);
            float x10 = __uint_as_float(u10[c] << 16), s10 = __uint_as_float(u10[c] & 0xffff0000u);
            float x11 = __uint_as_float(u11[c] << 16), s11 = __uint_as_float(u11[c] & 0xffff0000u);
            float vx = w00 * x00; vx = fmaf(w01, x01, vx); vx = fmaf(w10, x10, vx); vx = fmaf(w11, x11, vx);
            float vs = w00 * s00; vs = fmaf(w01, s01, vs); vs = fmaf(w10, s10, vs); vs = fmaf(w11, s11, vs);
            vx *= m1;
            vs *= m2;
#pragma unroll
            for (int o = 0; o < 8; o++) {
                const float wv = wdc[((size_t)((g * 8 + o) * 8 + c)) * 9 + kk];
                accx[o] = fmaf(vx, wv, accx[o]);
                accs[o] = fmaf(vs, wv, accs[o]);
            }
        }
    }

#pragma unroll
    for (int o = 0; o < 8; o++) {
        const float bv = bdc[g * 8 + o];
        outx[((size_t)(b * COO + g * 8 + o)) * HWC + pix] = accx[o] + bv;
        outs[((size_t)(b * COO + g * 8 + o)) * HWC + pix] = accs[o] + bv;
    }
}

// ---------------------------------------------------------------------------
extern "C" void kernel_launch(void* const* d_in, const int* in_sizes, int n_in,
                              void* d_out, int out_size, void* d_ws, size_t ws_size,
                              hipStream_t stream) {
    const float* x      = (const float*)d_in[0];
    const float* share  = (const float*)d_in[1];
    const float* offf   = (const float*)d_in[2];
    const float* w_om   = (const float*)d_in[3];
    const float* b_om   = (const float*)d_in[4];
    const float* w_em1  = (const float*)d_in[5];
    const float* b_em1  = (const float*)d_in[6];
    const float* w_em2  = (const float*)d_in[7];
    const float* b_em2  = (const float*)d_in[8];
    const float* w_dc   = (const float*)d_in[9];
    const float* b_dc   = (const float*)d_in[10];

    // Workspace layout
    unsigned int* xs = (unsigned int*)d_ws;           // 4194304 u32
    unsigned short* us = (unsigned short*)(xs + 4194304);
    unsigned short* sc16   = us;                      // 4194304 ush (share c16)
    unsigned short* oc16   = sc16 + 4194304;          // 4194304 (offf c16)
    unsigned short* emm    = oc16 + 4194304;          // 4194304 (em_mid c16)
    unsigned short* om_b   = emm + 4194304;           // 14155776 (om NCHW bf16)
    unsigned short* em_b   = om_b + 14155776;         // 4718592 (em NCHW bf16)
    unsigned short* wp_om  = em_b + 4718592;          // 129024
    unsigned short* wp_em1 = wp_om + 129024;          // 73728
    unsigned short* wp_em2 = wp_em1 + 73728;          // 55296

    float* outx = (float*)d_out;
    float* outs = outx + 4194304;

    dim3 blk(256);

    // Repack inputs
    pack_xs_kernel<<<(4194304 + 255) / 256, blk, 0, stream>>>(x, share, xs, 4194304);
    to_c16_kernel<<<dim3(HWC / 64, BB), blk, 0, stream>>>(share, sc16);
    to_c16_kernel<<<dim3(HWC / 64, BB), blk, 0, stream>>>(offf, oc16);

    // Pack weights
    pack_w_kernel<<<(129024 + 255) / 256, blk, 0, stream>>>(w_om,  wp_om,  216, 224, 64,  129024);
    pack_w_kernel<<<(73728  + 255) / 256, blk, 0, stream>>>(w_em1, wp_em1, 64,  64,  128, 73728);
    pack_w_kernel<<<(55296  + 255) / 256, blk, 0, stream>>>(w_em2, wp_em2, 72,  96,  64,  55296);

    // om = conv(offset_feat) 64->216, sigmoid on mask channels, NCHW bf16
    conv_mfma_kernel<1><<<dim3(BB * HH / 4, 7), blk, 0, stream>>>(
        oc16, nullptr, wp_om, b_om, om_b, 216, 224, 2, 3);
    // em_mid = leaky(conv(concat(share, offf))) 128->64, c16 bf16
    conv_mfma_kernel<2><<<dim3(BB * HH / 4, 2), blk, 0, stream>>>(
        sc16, oc16, wp_em1, b_em1, emm, 64, 64, 3, 1);
    // em = sigmoid(conv(em_mid)) 64->72, NCHW bf16
    conv_mfma_kernel<1><<<dim3(BB * HH / 4, 3), blk, 0, stream>>>(
        emm, nullptr, wp_em2, b_em2, em_b, 72, 96, 2, 2);

    // fused dual deformable conv (LDS-staged gathers)
    deform_fused_kernel<<<dim3(BB * GG * 64), blk, 0, stream>>>(
        xs, om_b, em_b, w_dc, b_dc, outx, outs);
}

// Round 5
// 522.930 us; speedup vs baseline: 1.1310x; 1.1310x over previous
//
#include <hip/hip_runtime.h>
#include <math.h>

// Problem constants
#define BB 4
#define CC 64
#define HH 128
#define WW 128
#define GG 8
#define COO 64
#define HWC (HH*WW)

typedef float f32x16 __attribute__((ext_vector_type(16)));
typedef __bf16 bf16x8 __attribute__((ext_vector_type(8)));

__device__ __forceinline__ unsigned short bf16_rn(float f) {
    unsigned int u = __float_as_uint(f);
    unsigned int r = (u + 0x7fffu + ((u >> 16) & 1u)) >> 16;
    return (unsigned short)r;
}
__device__ __forceinline__ float b2f(unsigned short u) {
    return __uint_as_float(((unsigned int)u) << 16);
}

// ---------------------------------------------------------------------------
// NCHW fp32 -> channel-blocked bf16 "c16": out[((b*4+cg)*HWC + pix)*16 + ci].
// ---------------------------------------------------------------------------
__global__ __launch_bounds__(256) void to_c16_kernel(const float* __restrict__ in,
                                                     unsigned short* __restrict__ out) {
    __shared__ unsigned short lds[64][66];
    const int b = blockIdx.y;
    const int pix0 = blockIdx.x * 64;
    const int t = threadIdx.x;
    {
        const int p = t & 63, q = t >> 6;
#pragma unroll
        for (int i = 0; i < 16; i++) {
            int c = i * 4 + q;
            lds[c][p] = bf16_rn(in[((size_t)b * 64 + c) * HWC + pix0 + p]);
        }
    }
    __syncthreads();
    {
        const int pl = t & 63, cg = t >> 6;
        unsigned int u[8];
#pragma unroll
        for (int j = 0; j < 8; j++) {
            unsigned int lo = lds[cg * 16 + 2 * j][pl];
            unsigned int hi = lds[cg * 16 + 2 * j + 1][pl];
            u[j] = lo | (hi << 16);
        }
        unsigned int* dst = (unsigned int*)(out + ((size_t)(b * 4 + cg) * HWC + pix0 + pl) * 16);
        *(uint4*)dst = make_uint4(u[0], u[1], u[2], u[3]);
        *(uint4*)(dst + 4) = make_uint4(u[4], u[5], u[6], u[7]);
    }
}

// ---------------------------------------------------------------------------
// Interleave x & share (NCHW fp32) into NCHW uint32: lo16=bf16(x),
// hi16=bf16(share).
// ---------------------------------------------------------------------------
__global__ __launch_bounds__(256) void pack_xs_kernel(const float* __restrict__ x,
                                                      const float* __restrict__ s,
                                                      unsigned int* __restrict__ xs, int n) {
    int i = blockIdx.x * 256 + threadIdx.x;
    if (i < n) {
        xs[i] = (unsigned int)bf16_rn(x[i]) | ((unsigned int)bf16_rn(s[i]) << 16);
    }
}

// ---------------------------------------------------------------------------
// Pack conv weights into MFMA A-fragment order.
// ---------------------------------------------------------------------------
__global__ void pack_w_kernel(const float* __restrict__ w, unsigned short* __restrict__ wp,
                              int Cout, int COP, int CinTot, int n) {
    int idx = blockIdx.x * 256 + threadIdx.x;
    if (idx >= n) return;
    int i  = idx & 15;
    int co = (idx >> 4) % COP;
    int t  = idx / (16 * COP);       // t = (seg*9+kk)*4+cg
    int cg = t & 3;
    int kk = (t >> 2) % 9;
    int seg = t / 36;
    int cin = seg * 64 + cg * 16 + i;
    float v = (co < Cout) ? w[((size_t)co * CinTot + cin) * 9 + kk] : 0.f;
    wp[idx] = bf16_rn(v);
}

// ---------------------------------------------------------------------------
// Implicit-GEMM 3x3 conv via mfma_f32_32x32x16_bf16, inputs in c16 layout.
// launch_bounds(256,2): empirically (256,4) caps at 64 arch-VGPRs -> spills.
// ---------------------------------------------------------------------------
template<int NSEG>
__global__ __launch_bounds__(256, 2) void conv_mfma_kernel(
    const unsigned short* __restrict__ in0,
    const unsigned short* __restrict__ in1,
    const unsigned short* __restrict__ wp,
    const float* __restrict__ bias,
    void* __restrict__ out,
    int Cout, int COP, int out_mode, int act)
{
    const int lane = threadIdx.x & 63;
    const int wid  = threadIdx.x >> 6;
    const int l31  = lane & 31;
    const int half = lane >> 5;
    const int b    = blockIdx.x >> 5;
    const int r    = ((blockIdx.x & 31) << 2) + wid;   // image row, wave-uniform
    const int co0  = blockIdx.y * 32;

    f32x16 acc[4];
#pragma unroll
    for (int nt = 0; nt < 4; nt++)
#pragma unroll
        for (int rg = 0; rg < 16; rg++) acc[nt][rg] = 0.f;

    bf16x8 bz;
#pragma unroll
    for (int i = 0; i < 8; i++) bz[i] = (__bf16)0.f;

#pragma unroll
    for (int seg = 0; seg < NSEG; seg++) {
        const unsigned short* in = seg ? in1 : in0;
        const unsigned short* inb = in + (size_t)b * 4 * HWC * 16;
        for (int kk = 0; kk < 9; kk++) {
            const int rr = r + kk / 3 - 1;
            if ((unsigned)rr < (unsigned)HH) {
                const int dxo = kk % 3 - 1;
#pragma unroll
                for (int cg = 0; cg < 4; cg++) {
                    bf16x8 afrag = *(const bf16x8*)(wp +
                        ((size_t)(((seg * 9 + kk) * 4 + cg) * COP + co0 + l31) * 16 + half * 8));
                    const size_t plane = ((size_t)cg * HWC + (size_t)rr * WW) * 16;
#pragma unroll
                    for (int nt = 0; nt < 4; nt++) {
                        const int cc = nt * 32 + l31 + dxo;
                        bf16x8 bfrag = bz;
                        if ((unsigned)cc < (unsigned)WW)
                            bfrag = *(const bf16x8*)(inb + plane + (size_t)cc * 16 + half * 8);
                        acc[nt] = __builtin_amdgcn_mfma_f32_32x32x16_bf16(afrag, bfrag, acc[nt], 0, 0, 0);
                    }
                }
            }
        }
    }

    // Epilogue: D layout col(pix)=lane&31, row(co)=(rg&3)+8*(rg>>2)+4*half
#pragma unroll
    for (int nt = 0; nt < 4; nt++) {
#pragma unroll
        for (int rg = 0; rg < 16; rg++) {
            const int row = (rg & 3) + 8 * (rg >> 2) + 4 * half;
            const int co = co0 + row;
            if (co < Cout) {
                float v = acc[nt][rg] + bias[co];
                if (act == 1)      v = (v >= 0.f) ? v : 0.1f * v;
                else if (act == 2) v = 1.f / (1.f + __expf(-v));
                else if (act == 3 && co >= 144) v = 1.f / (1.f + __expf(-v));
                const int pix = r * WW + nt * 32 + l31;
                if (out_mode == 2)
                    ((unsigned short*)out)[((size_t)b * Cout + co) * HWC + pix] = bf16_rn(v);
                else // c16
                    ((unsigned short*)out)[((size_t)(b * 4 + (co >> 4)) * HWC + pix) * 16 + (co & 15)] = bf16_rn(v);
            }
        }
    }
}

// ---------------------------------------------------------------------------
// Fused dual modulated deformable conv with LDS window staging.
// Block = one (b,g) x 16x16 tile; 24x24 clamped window of 8 interleaved
// channels staged CHANNEL-INNERMOST: lds[(sy*24+sx)*8 + c] -> each bilinear
// corner's 8 channels are two aligned ds_read_b128 (8 LDS instrs per kk
// instead of 32 stride-600 b32 reads). launch_bounds(256,2): (256,4) caps
// VGPRs at 64 and caused 670 MB of scratch spill in R3/R4.
// ---------------------------------------------------------------------------
__global__ __launch_bounds__(256, 2) void deform_fused_kernel(
    const unsigned int* __restrict__ xs,
    const unsigned short* __restrict__ om, const unsigned short* __restrict__ em,
    const float* __restrict__ wdc, const float* __restrict__ bdc,
    float* __restrict__ outx, float* __restrict__ outs)
{
    __shared__ __align__(16) unsigned int lds[24 * 24 * 8];   // 18432 B

    const int bg = blockIdx.x >> 6;           // b*8+g
    const int b = bg >> 3, g = bg & 7;
    const int tile = blockIdx.x & 63;
    const int r0 = (tile >> 3) << 4;
    const int c0 = (tile & 7) << 4;
    const int tx = threadIdx.x & 15, ty = threadIdx.x >> 4;
    const int h = r0 + ty, w = c0 + tx;
    const int wr0 = r0 - 4, wc0 = c0 - 4;

    const unsigned int* xsb = xs + ((size_t)b * 64 + g * 8) * HWC;

    // Stage: slot = c*576 + sy*24 + sx (sx innermost -> global coalesced)
#pragma unroll
    for (int i = 0; i < 18; i++) {
        unsigned int slot = (unsigned int)threadIdx.x + i * 256u;   // 0..4607
        unsigned int sx = slot % 24u;
        unsigned int t2 = slot / 24u;
        unsigned int sy = t2 % 24u;
        unsigned int c  = t2 / 24u;
        int iy = min(max(wr0 + (int)sy, 0), HH - 1);
        int ix = min(max(wc0 + (int)sx, 0), WW - 1);
        lds[(sy * 24u + sx) * 8u + c] = xsb[(size_t)c * HWC + iy * WW + ix];
    }

    // Hoist offset/mask loads
    const int pix = h * WW + w;
    const unsigned short* omb = om + (size_t)b * 216 * HWC + pix;
    const unsigned short* emb = em + (size_t)b * 72 * HWC + pix;
    float dys[9], dxs[9], m1s[9], m2s[9];
#pragma unroll
    for (int kk = 0; kk < 9; kk++) {
        dys[kk] = b2f(omb[(size_t)(g * 18 + kk * 2) * HWC]);
        dxs[kk] = b2f(omb[(size_t)(g * 18 + kk * 2 + 1) * HWC]);
        m1s[kk] = b2f(omb[(size_t)(144 + g * 9 + kk) * HWC]);
        m2s[kk] = b2f(emb[(size_t)(g * 9 + kk) * HWC]);
    }

    __syncthreads();

    float accx[8], accs[8];
#pragma unroll
    for (int o = 0; o < 8; o++) { accx[o] = 0.f; accs[o] = 0.f; }

#pragma unroll
    for (int kk = 0; kk < 9; kk++) {
        const float py = (float)(h - 1 + kk / 3) + dys[kk];
        const float px = (float)(w - 1 + kk % 3) + dxs[kk];
        const float y0f = floorf(py), x0f = floorf(px);
        const float ly = py - y0f, lx = px - x0f;
        const int y0 = (int)y0f, x0 = (int)x0f;
        const int y1 = y0 + 1, x1 = x0 + 1;
        const bool vy0 = (y0 >= 0) && (y0 < HH), vy1 = (y1 >= 0) && (y1 < HH);
        const bool vx0 = (x0 >= 0) && (x0 < WW), vx1 = (x1 >= 0) && (x1 < WW);
        float w00 = (1.f - ly) * (1.f - lx); if (!(vy0 && vx0)) w00 = 0.f;
        float w01 = (1.f - ly) * lx;         if (!(vy0 && vx1)) w01 = 0.f;
        float w10 = ly * (1.f - lx);         if (!(vy1 && vx0)) w10 = 0.f;
        float w11 = ly * lx;                 if (!(vy1 && vx1)) w11 = 0.f;
        const int cy0 = min(max(y0, 0), HH - 1), cy1 = min(max(y1, 0), HH - 1);
        const int cx0 = min(max(x0, 0), WW - 1), cx1 = min(max(x1, 0), WW - 1);
        const float m1 = m1s[kk], m2 = m2s[kk];

        const int sy0 = cy0 - wr0, sy1 = cy1 - wr0;
        const int sx0 = cx0 - wc0, sx1 = cx1 - wc0;
        const bool inw = (sy0 >= 0) && (sy1 < 24) && (sx0 >= 0) && (sx1 < 24);

        unsigned int u00[8], u01[8], u10[8], u11[8];
        if (inw) {
            const int p00 = (sy0 * 24 + sx0) * 8, p01 = (sy0 * 24 + sx1) * 8;
            const int p10 = (sy1 * 24 + sx0) * 8, p11 = (sy1 * 24 + sx1) * 8;
            uint4 q;
            q = *(const uint4*)(lds + p00);     u00[0]=q.x; u00[1]=q.y; u00[2]=q.z; u00[3]=q.w;
            q = *(const uint4*)(lds + p00 + 4); u00[4]=q.x; u00[5]=q.y; u00[6]=q.z; u00[7]=q.w;
            q = *(const uint4*)(lds + p01);     u01[0]=q.x; u01[1]=q.y; u01[2]=q.z; u01[3]=q.w;
            q = *(const uint4*)(lds + p01 + 4); u01[4]=q.x; u01[5]=q.y; u01[6]=q.z; u01[7]=q.w;
            q = *(const uint4*)(lds + p10);     u10[0]=q.x; u10[1]=q.y; u10[2]=q.z; u10[3]=q.w;
            q = *(const uint4*)(lds + p10 + 4); u10[4]=q.x; u10[5]=q.y; u10[6]=q.z; u10[7]=q.w;
            q = *(const uint4*)(lds + p11);     u11[0]=q.x; u11[1]=q.y; u11[2]=q.z; u11[3]=q.w;
            q = *(const uint4*)(lds + p11 + 4); u11[4]=q.x; u11[5]=q.y; u11[6]=q.z; u11[7]=q.w;
        } else {
            const int i00 = cy0 * WW + cx0, i01 = cy0 * WW + cx1;
            const int i10 = cy1 * WW + cx0, i11 = cy1 * WW + cx1;
#pragma unroll
            for (int c = 0; c < 8; c++) {
                const unsigned int* xc = xsb + (size_t)c * HWC;
                u00[c] = xc[i00]; u01[c] = xc[i01];
                u10[c] = xc[i10]; u11[c] = xc[i11];
            }
        }

#pragma unroll
        for (int c = 0; c < 8; c++) {
            float x00 = __uint_as_float(u00[c] << 16), s00 = __uint_as_float(u00[c] & 0xffff0000u);
            float x01 = __uint_as_float(u01[c] << 16), s01 = __uint_as_float(u01[c] & 0xffff0000u);
            float x10 = __uint_as_float(u10[c] << 16), s10 = __uint_as_float(u10[c] & 0xffff0000u);
            float x11 = __uint_as_float(u11[c] << 16), s11 = __uint_as_float(u11[c] & 0xffff0000u);
            float vx = w00 * x00; vx = fmaf(w01, x01, vx); vx = fmaf(w10, x10, vx); vx = fmaf(w11, x11, vx);
            float vs = w00 * s00; vs = fmaf(w01, s01, vs); vs = fmaf(w10, s10, vs); vs = fmaf(w11, s11, vs);
            vx *= m1;
            vs *= m2;
#pragma unroll
            for (int o = 0; o < 8; o++) {
                const float wv = wdc[((size_t)((g * 8 + o) * 8 + c)) * 9 + kk];
                accx[o] = fmaf(vx, wv, accx[o]);
                accs[o] = fmaf(vs, wv, accs[o]);
            }
        }
    }

#pragma unroll
    for (int o = 0; o < 8; o++) {
        const float bv = bdc[g * 8 + o];
        outx[((size_t)(b * COO + g * 8 + o)) * HWC + pix] = accx[o] + bv;
        outs[((size_t)(b * COO + g * 8 + o)) * HWC + pix] = accs[o] + bv;
    }
}

// ---------------------------------------------------------------------------
extern "C" void kernel_launch(void* const* d_in, const int* in_sizes, int n_in,
                              void* d_out, int out_size, void* d_ws, size_t ws_size,
                              hipStream_t stream) {
    const float* x      = (const float*)d_in[0];
    const float* share  = (const float*)d_in[1];
    const float* offf   = (const float*)d_in[2];
    const float* w_om   = (const float*)d_in[3];
    const float* b_om   = (const float*)d_in[4];
    const float* w_em1  = (const float*)d_in[5];
    const float* b_em1  = (const float*)d_in[6];
    const float* w_em2  = (const float*)d_in[7];
    const float* b_em2  = (const float*)d_in[8];
    const float* w_dc   = (const float*)d_in[9];
    const float* b_dc   = (const float*)d_in[10];

    // Workspace layout
    unsigned int* xs = (unsigned int*)d_ws;           // 4194304 u32
    unsigned short* us = (unsigned short*)(xs + 4194304);
    unsigned short* sc16   = us;                      // 4194304 ush (share c16)
    unsigned short* oc16   = sc16 + 4194304;          // 4194304 (offf c16)
    unsigned short* emm    = oc16 + 4194304;          // 4194304 (em_mid c16)
    unsigned short* om_b   = emm + 4194304;           // 14155776 (om NCHW bf16)
    unsigned short* em_b   = om_b + 14155776;         // 4718592 (em NCHW bf16)
    unsigned short* wp_om  = em_b + 4718592;          // 129024
    unsigned short* wp_em1 = wp_om + 129024;          // 73728
    unsigned short* wp_em2 = wp_em1 + 73728;          // 55296

    float* outx = (float*)d_out;
    float* outs = outx + 4194304;

    dim3 blk(256);

    // Repack inputs
    pack_xs_kernel<<<(4194304 + 255) / 256, blk, 0, stream>>>(x, share, xs, 4194304);
    to_c16_kernel<<<dim3(HWC / 64, BB), blk, 0, stream>>>(share, sc16);
    to_c16_kernel<<<dim3(HWC / 64, BB), blk, 0, stream>>>(offf, oc16);

    // Pack weights
    pack_w_kernel<<<(129024 + 255) / 256, blk, 0, stream>>>(w_om,  wp_om,  216, 224, 64,  129024);
    pack_w_kernel<<<(73728  + 255) / 256, blk, 0, stream>>>(w_em1, wp_em1, 64,  64,  128, 73728);
    pack_w_kernel<<<(55296  + 255) / 256, blk, 0, stream>>>(w_em2, wp_em2, 72,  96,  64,  55296);

    // om = conv(offset_feat) 64->216, sigmoid on mask channels, NCHW bf16
    conv_mfma_kernel<1><<<dim3(BB * HH / 4, 7), blk, 0, stream>>>(
        oc16, nullptr, wp_om, b_om, om_b, 216, 224, 2, 3);
    // em_mid = leaky(conv(concat(share, offf))) 128->64, c16 bf16
    conv_mfma_kernel<2><<<dim3(BB * HH / 4, 2), blk, 0, stream>>>(
        sc16, oc16, wp_em1, b_em1, emm, 64, 64, 3, 1);
    // em = sigmoid(conv(em_mid)) 64->72, NCHW bf16
    conv_mfma_kernel<1><<<dim3(BB * HH / 4, 3), blk, 0, stream>>>(
        emm, nullptr, wp_em2, b_em2, em_b, 72, 96, 2, 2);

    // fused dual deformable conv (LDS-staged gathers)
    deform_fused_kernel<<<dim3(BB * GG * 64), blk, 0, stream>>>(
        xs, om_b, em_b, w_dc, b_dc, outx, outs);
}

// Round 6
// 331.416 us; speedup vs baseline: 1.7846x; 1.5779x over previous
//
#include <hip/hip_runtime.h>
#include <math.h>

// Problem constants
#define BB 4
#define CC 64
#define HH 128
#define WW 128
#define GG 8
#define COO 64
#define HWC (HH*WW)

// Deform LDS layout: pixel stride 12 u32 (48 B, 16B aligned), row padded to 26
#define DPAD 12
#define DROW 26

typedef float f32x16 __attribute__((ext_vector_type(16)));
typedef __bf16 bf16x8 __attribute__((ext_vector_type(8)));

__device__ __forceinline__ unsigned short bf16_rn(float f) {
    unsigned int u = __float_as_uint(f);
    unsigned int r = (u + 0x7fffu + ((u >> 16) & 1u)) >> 16;
    return (unsigned short)r;
}
__device__ __forceinline__ float b2f(unsigned short u) {
    return __uint_as_float(((unsigned int)u) << 16);
}

// ---------------------------------------------------------------------------
// NCHW fp32 -> channel-blocked bf16 "c16": out[((b*4+cg)*HWC + pix)*16 + ci].
// ---------------------------------------------------------------------------
__global__ __launch_bounds__(256) void to_c16_kernel(const float* __restrict__ in,
                                                     unsigned short* __restrict__ out) {
    __shared__ unsigned short lds[64][66];
    const int b = blockIdx.y;
    const int pix0 = blockIdx.x * 64;
    const int t = threadIdx.x;
    {
        const int p = t & 63, q = t >> 6;
#pragma unroll
        for (int i = 0; i < 16; i++) {
            int c = i * 4 + q;
            lds[c][p] = bf16_rn(in[((size_t)b * 64 + c) * HWC + pix0 + p]);
        }
    }
    __syncthreads();
    {
        const int pl = t & 63, cg = t >> 6;
        unsigned int u[8];
#pragma unroll
        for (int j = 0; j < 8; j++) {
            unsigned int lo = lds[cg * 16 + 2 * j][pl];
            unsigned int hi = lds[cg * 16 + 2 * j + 1][pl];
            u[j] = lo | (hi << 16);
        }
        unsigned int* dst = (unsigned int*)(out + ((size_t)(b * 4 + cg) * HWC + pix0 + pl) * 16);
        *(uint4*)dst = make_uint4(u[0], u[1], u[2], u[3]);
        *(uint4*)(dst + 4) = make_uint4(u[4], u[5], u[6], u[7]);
    }
}

// ---------------------------------------------------------------------------
// Interleave x & share (NCHW fp32) into NCHW uint32: lo16=bf16(x), hi16=bf16(share).
// ---------------------------------------------------------------------------
__global__ __launch_bounds__(256) void pack_xs_kernel(const float* __restrict__ x,
                                                      const float* __restrict__ s,
                                                      unsigned int* __restrict__ xs, int n) {
    int i = blockIdx.x * 256 + threadIdx.x;
    if (i < n) {
        xs[i] = (unsigned int)bf16_rn(x[i]) | ((unsigned int)bf16_rn(s[i]) << 16);
    }
}

// ---------------------------------------------------------------------------
// Pack conv weights into MFMA A-fragment order.
// ---------------------------------------------------------------------------
__global__ void pack_w_kernel(const float* __restrict__ w, unsigned short* __restrict__ wp,
                              int Cout, int COP, int CinTot, int n) {
    int idx = blockIdx.x * 256 + threadIdx.x;
    if (idx >= n) return;
    int i  = idx & 15;
    int co = (idx >> 4) % COP;
    int t  = idx / (16 * COP);       // t = (seg*9+kk)*4+cg
    int cg = t & 3;
    int kk = (t >> 2) % 9;
    int seg = t / 36;
    int cin = seg * 64 + cg * 16 + i;
    float v = (co < Cout) ? w[((size_t)co * CinTot + cin) * 9 + kk] : 0.f;
    wp[idx] = bf16_rn(v);
}

// ---------------------------------------------------------------------------
// Implicit-GEMM 3x3 conv via mfma_f32_32x32x16_bf16, inputs in c16 layout.
// NO min-waves clause: (256,4) capped VGPRs at 64, (256,2) at 128 -> both
// forced scratch spill (the 64-acc f32x16[4] + fragments need ~110 regs).
// ---------------------------------------------------------------------------
template<int NSEG>
__global__ __launch_bounds__(256) void conv_mfma_kernel(
    const unsigned short* __restrict__ in0,
    const unsigned short* __restrict__ in1,
    const unsigned short* __restrict__ wp,
    const float* __restrict__ bias,
    void* __restrict__ out,
    int Cout, int COP, int out_mode, int act)
{
    const int lane = threadIdx.x & 63;
    const int wid  = threadIdx.x >> 6;
    const int l31  = lane & 31;
    const int half = lane >> 5;
    const int b    = blockIdx.x >> 5;
    const int r    = ((blockIdx.x & 31) << 2) + wid;   // image row, wave-uniform
    const int co0  = blockIdx.y * 32;

    f32x16 acc[4];
#pragma unroll
    for (int nt = 0; nt < 4; nt++)
#pragma unroll
        for (int rg = 0; rg < 16; rg++) acc[nt][rg] = 0.f;

    bf16x8 bz;
#pragma unroll
    for (int i = 0; i < 8; i++) bz[i] = (__bf16)0.f;

#pragma unroll
    for (int seg = 0; seg < NSEG; seg++) {
        const unsigned short* in = seg ? in1 : in0;
        const unsigned short* inb = in + (size_t)b * 4 * HWC * 16;
        for (int kk = 0; kk < 9; kk++) {
            const int rr = r + kk / 3 - 1;
            if ((unsigned)rr < (unsigned)HH) {
                const int dxo = kk % 3 - 1;
#pragma unroll
                for (int cg = 0; cg < 4; cg++) {
                    bf16x8 afrag = *(const bf16x8*)(wp +
                        ((size_t)(((seg * 9 + kk) * 4 + cg) * COP + co0 + l31) * 16 + half * 8));
                    const size_t plane = ((size_t)cg * HWC + (size_t)rr * WW) * 16;
#pragma unroll
                    for (int nt = 0; nt < 4; nt++) {
                        const int cc = nt * 32 + l31 + dxo;
                        bf16x8 bfrag = bz;
                        if ((unsigned)cc < (unsigned)WW)
                            bfrag = *(const bf16x8*)(inb + plane + (size_t)cc * 16 + half * 8);
                        acc[nt] = __builtin_amdgcn_mfma_f32_32x32x16_bf16(afrag, bfrag, acc[nt], 0, 0, 0);
                    }
                }
            }
        }
    }

    // Epilogue: D layout col(pix)=lane&31, row(co)=(rg&3)+8*(rg>>2)+4*half
#pragma unroll
    for (int nt = 0; nt < 4; nt++) {
#pragma unroll
        for (int rg = 0; rg < 16; rg++) {
            const int row = (rg & 3) + 8 * (rg >> 2) + 4 * half;
            const int co = co0 + row;
            if (co < Cout) {
                float v = acc[nt][rg] + bias[co];
                if (act == 1)      v = (v >= 0.f) ? v : 0.1f * v;
                else if (act == 2) v = 1.f / (1.f + __expf(-v));
                else if (act == 3 && co >= 144) v = 1.f / (1.f + __expf(-v));
                const int pix = r * WW + nt * 32 + l31;
                if (out_mode == 2)
                    ((unsigned short*)out)[((size_t)b * Cout + co) * HWC + pix] = bf16_rn(v);
                else // c16
                    ((unsigned short*)out)[((size_t)(b * 4 + (co >> 4)) * HWC + pix) * 16 + (co & 15)] = bf16_rn(v);
            }
        }
    }
}

// ---------------------------------------------------------------------------
// Fused dual modulated deformable conv, LDS-staged, register-pressure-tuned:
//  - om/em loads INSIDE each unrolled kk iter (short live ranges, -36 regs)
//  - gathers processed in 2 chunks of 4 channels (16 gather regs, not 32)
//  - LDS: pixel stride 12 u32 (48 B), rows padded to 26 -> worst 2-way bank
//    aliasing (free); b128-aligned chunk reads
//  - no min-waves clause (128-cap caused 620 MB scratch traffic in R5)
// ---------------------------------------------------------------------------
__global__ __launch_bounds__(256) void deform_fused_kernel(
    const unsigned int* __restrict__ xs,
    const unsigned short* __restrict__ om, const unsigned short* __restrict__ em,
    const float* __restrict__ wdc, const float* __restrict__ bdc,
    float* __restrict__ outx, float* __restrict__ outs)
{
    __shared__ __align__(16) unsigned int lds[24 * DROW * DPAD];   // 29952 B

    const int bg = blockIdx.x >> 6;           // b*8+g
    const int b = bg >> 3, g = bg & 7;
    const int tile = blockIdx.x & 63;
    const int r0 = (tile >> 3) << 4;
    const int c0 = (tile & 7) << 4;
    const int tx = threadIdx.x & 15, ty = threadIdx.x >> 4;
    const int h = r0 + ty, w = c0 + tx;
    const int wr0 = r0 - 4, wc0 = c0 - 4;

    const unsigned int* xsb = xs + ((size_t)b * 64 + g * 8) * HWC;

    // Stage 8 ch x 24x24 clamped window; slot = c*576 + sy*24 + sx
#pragma unroll
    for (int i = 0; i < 18; i++) {
        unsigned int slot = (unsigned int)threadIdx.x + i * 256u;   // 0..4607
        unsigned int sx = slot % 24u;
        unsigned int t2 = slot / 24u;
        unsigned int sy = t2 % 24u;
        unsigned int c  = t2 / 24u;
        int iy = min(max(wr0 + (int)sy, 0), HH - 1);
        int ix = min(max(wc0 + (int)sx, 0), WW - 1);
        lds[(sy * DROW + sx) * DPAD + c] = xsb[(size_t)c * HWC + iy * WW + ix];
    }

    __syncthreads();

    const int pix = h * WW + w;
    const unsigned short* omb = om + (size_t)b * 216 * HWC + pix + (size_t)g * 18 * HWC;
    const unsigned short* mmb = om + (size_t)b * 216 * HWC + pix + (size_t)(144 + g * 9) * HWC;
    const unsigned short* emb = em + (size_t)b * 72 * HWC + pix + (size_t)g * 9 * HWC;

    float accx[8], accs[8];
#pragma unroll
    for (int o = 0; o < 8; o++) { accx[o] = 0.f; accs[o] = 0.f; }

#pragma unroll
    for (int kk = 0; kk < 9; kk++) {
        const float dy = b2f(omb[(size_t)(kk * 2) * HWC]);
        const float dx = b2f(omb[(size_t)(kk * 2 + 1) * HWC]);
        const float m1 = b2f(mmb[(size_t)kk * HWC]);
        const float m2 = b2f(emb[(size_t)kk * HWC]);

        const float py = (float)(h - 1 + kk / 3) + dy;
        const float px = (float)(w - 1 + kk % 3) + dx;
        const float y0f = floorf(py), x0f = floorf(px);
        const float ly = py - y0f, lx = px - x0f;
        const int y0 = (int)y0f, x0 = (int)x0f;
        const int y1 = y0 + 1, x1 = x0 + 1;
        const bool vy0 = (y0 >= 0) && (y0 < HH), vy1 = (y1 >= 0) && (y1 < HH);
        const bool vx0 = (x0 >= 0) && (x0 < WW), vx1 = (x1 >= 0) && (x1 < WW);
        float w00 = (1.f - ly) * (1.f - lx); if (!(vy0 && vx0)) w00 = 0.f;
        float w01 = (1.f - ly) * lx;         if (!(vy0 && vx1)) w01 = 0.f;
        float w10 = ly * (1.f - lx);         if (!(vy1 && vx0)) w10 = 0.f;
        float w11 = ly * lx;                 if (!(vy1 && vx1)) w11 = 0.f;
        const int cy0 = min(max(y0, 0), HH - 1), cy1 = min(max(y1, 0), HH - 1);
        const int cx0 = min(max(x0, 0), WW - 1), cx1 = min(max(x1, 0), WW - 1);

        const int sy0 = cy0 - wr0, sy1 = cy1 - wr0;
        const int sx0 = cx0 - wc0, sx1 = cx1 - wc0;
        const bool inw = (sy0 >= 0) && (sy1 < 24) && (sx0 >= 0) && (sx1 < 24);

        const float* wk = wdc + (size_t)g * 8 * 8 * 9 + kk;   // wk[(o*8+c)*9]

        if (__builtin_expect(inw, 1)) {
            const int p00 = (sy0 * DROW + sx0) * DPAD, p01 = (sy0 * DROW + sx1) * DPAD;
            const int p10 = (sy1 * DROW + sx0) * DPAD, p11 = (sy1 * DROW + sx1) * DPAD;
#pragma unroll
            for (int ch = 0; ch < 2; ch++) {
                uint4 qa = *(const uint4*)(lds + p00 + ch * 4);
                uint4 qb = *(const uint4*)(lds + p01 + ch * 4);
                uint4 qc = *(const uint4*)(lds + p10 + ch * 4);
                uint4 qd = *(const uint4*)(lds + p11 + ch * 4);
                const unsigned int ua[4] = {qa.x, qa.y, qa.z, qa.w};
                const unsigned int ub[4] = {qb.x, qb.y, qb.z, qb.w};
                const unsigned int uc[4] = {qc.x, qc.y, qc.z, qc.w};
                const unsigned int ud[4] = {qd.x, qd.y, qd.z, qd.w};
#pragma unroll
                for (int j = 0; j < 4; j++) {
                    const int c = ch * 4 + j;
                    float x00 = __uint_as_float(ua[j] << 16), s00 = __uint_as_float(ua[j] & 0xffff0000u);
                    float x01 = __uint_as_float(ub[j] << 16), s01 = __uint_as_float(ub[j] & 0xffff0000u);
                    float x10 = __uint_as_float(uc[j] << 16), s10 = __uint_as_float(uc[j] & 0xffff0000u);
                    float x11 = __uint_as_float(ud[j] << 16), s11 = __uint_as_float(ud[j] & 0xffff0000u);
                    float vx = w00 * x00; vx = fmaf(w01, x01, vx); vx = fmaf(w10, x10, vx); vx = fmaf(w11, x11, vx);
                    float vs = w00 * s00; vs = fmaf(w01, s01, vs); vs = fmaf(w10, s10, vs); vs = fmaf(w11, s11, vs);
                    vx *= m1;
                    vs *= m2;
#pragma unroll
                    for (int o = 0; o < 8; o++) {
                        const float wv = wk[(size_t)(o * 8 + c) * 9];
                        accx[o] = fmaf(vx, wv, accx[o]);
                        accs[o] = fmaf(vs, wv, accs[o]);
                    }
                }
            }
        } else {
            const int i00 = cy0 * WW + cx0, i01 = cy0 * WW + cx1;
            const int i10 = cy1 * WW + cx0, i11 = cy1 * WW + cx1;
#pragma unroll
            for (int c = 0; c < 8; c++) {
                const unsigned int* xc = xsb + (size_t)c * HWC;
                unsigned int a = xc[i00], bq = xc[i01], cq = xc[i10], dq = xc[i11];
                float x00 = __uint_as_float(a << 16),  s00 = __uint_as_float(a & 0xffff0000u);
                float x01 = __uint_as_float(bq << 16), s01 = __uint_as_float(bq & 0xffff0000u);
                float x10 = __uint_as_float(cq << 16), s10 = __uint_as_float(cq & 0xffff0000u);
                float x11 = __uint_as_float(dq << 16), s11 = __uint_as_float(dq & 0xffff0000u);
                float vx = w00 * x00; vx = fmaf(w01, x01, vx); vx = fmaf(w10, x10, vx); vx = fmaf(w11, x11, vx);
                float vs = w00 * s00; vs = fmaf(w01, s01, vs); vs = fmaf(w10, s10, vs); vs = fmaf(w11, s11, vs);
                vx *= m1;
                vs *= m2;
#pragma unroll
                for (int o = 0; o < 8; o++) {
                    const float wv = wk[(size_t)(o * 8 + c) * 9];
                    accx[o] = fmaf(vx, wv, accx[o]);
                    accs[o] = fmaf(vs, wv, accs[o]);
                }
            }
        }
    }

#pragma unroll
    for (int o = 0; o < 8; o++) {
        const float bv = bdc[g * 8 + o];
        outx[((size_t)(b * COO + g * 8 + o)) * HWC + pix] = accx[o] + bv;
        outs[((size_t)(b * COO + g * 8 + o)) * HWC + pix] = accs[o] + bv;
    }
}

// ---------------------------------------------------------------------------
extern "C" void kernel_launch(void* const* d_in, const int* in_sizes, int n_in,
                              void* d_out, int out_size, void* d_ws, size_t ws_size,
                              hipStream_t stream) {
    const float* x      = (const float*)d_in[0];
    const float* share  = (const float*)d_in[1];
    const float* offf   = (const float*)d_in[2];
    const float* w_om   = (const float*)d_in[3];
    const float* b_om   = (const float*)d_in[4];
    const float* w_em1  = (const float*)d_in[5];
    const float* b_em1  = (const float*)d_in[6];
    const float* w_em2  = (const float*)d_in[7];
    const float* b_em2  = (const float*)d_in[8];
    const float* w_dc   = (const float*)d_in[9];
    const float* b_dc   = (const float*)d_in[10];

    // Workspace layout
    unsigned int* xs = (unsigned int*)d_ws;           // 4194304 u32
    unsigned short* us = (unsigned short*)(xs + 4194304);
    unsigned short* sc16   = us;                      // 4194304 ush (share c16)
    unsigned short* oc16   = sc16 + 4194304;          // 4194304 (offf c16)
    unsigned short* emm    = oc16 + 4194304;          // 4194304 (em_mid c16)
    unsigned short* om_b   = emm + 4194304;           // 14155776 (om NCHW bf16)
    unsigned short* em_b   = om_b + 14155776;         // 4718592 (em NCHW bf16)
    unsigned short* wp_om  = em_b + 4718592;          // 129024
    unsigned short* wp_em1 = wp_om + 129024;          // 73728
    unsigned short* wp_em2 = wp_em1 + 73728;          // 55296

    float* outx = (float*)d_out;
    float* outs = outx + 4194304;

    dim3 blk(256);

    // Repack inputs
    pack_xs_kernel<<<(4194304 + 255) / 256, blk, 0, stream>>>(x, share, xs, 4194304);
    to_c16_kernel<<<dim3(HWC / 64, BB), blk, 0, stream>>>(share, sc16);
    to_c16_kernel<<<dim3(HWC / 64, BB), blk, 0, stream>>>(offf, oc16);

    // Pack weights
    pack_w_kernel<<<(129024 + 255) / 256, blk, 0, stream>>>(w_om,  wp_om,  216, 224, 64,  129024);
    pack_w_kernel<<<(73728  + 255) / 256, blk, 0, stream>>>(w_em1, wp_em1, 64,  64,  128, 73728);
    pack_w_kernel<<<(55296  + 255) / 256, blk, 0, stream>>>(w_em2, wp_em2, 72,  96,  64,  55296);

    // om = conv(offset_feat) 64->216, sigmoid on mask channels, NCHW bf16
    conv_mfma_kernel<1><<<dim3(BB * HH / 4, 7), blk, 0, stream>>>(
        oc16, nullptr, wp_om, b_om, om_b, 216, 224, 2, 3);
    // em_mid = leaky(conv(concat(share, offf))) 128->64, c16 bf16
    conv_mfma_kernel<2><<<dim3(BB * HH / 4, 2), blk, 0, stream>>>(
        sc16, oc16, wp_em1, b_em1, emm, 64, 64, 3, 1);
    // em = sigmoid(conv(em_mid)) 64->72, NCHW bf16
    conv_mfma_kernel<1><<<dim3(BB * HH / 4, 3), blk, 0, stream>>>(
        emm, nullptr, wp_em2, b_em2, em_b, 72, 96, 2, 2);

    // fused dual deformable conv (LDS-staged gathers)
    deform_fused_kernel<<<dim3(BB * GG * 64), blk, 0, stream>>>(
        xs, om_b, em_b, w_dc, b_dc, outx, outs);
}

// Round 7
// 276.145 us; speedup vs baseline: 2.1418x; 1.2002x over previous
//
#include <hip/hip_runtime.h>
#include <math.h>

// Problem constants
#define BB 4
#define CC 64
#define HH 128
#define WW 128
#define GG 8
#define COO 64
#define HWC (HH*WW)

// Deform LDS layout: pixel stride 12 u32 (48 B, 16B aligned), row padded to 26
#define DPAD 12
#define DROW 26

typedef float f32x16 __attribute__((ext_vector_type(16)));
typedef __bf16 bf16x8 __attribute__((ext_vector_type(8)));

__device__ __forceinline__ unsigned short bf16_rn(float f) {
    unsigned int u = __float_as_uint(f);
    unsigned int r = (u + 0x7fffu + ((u >> 16) & 1u)) >> 16;
    return (unsigned short)r;
}
__device__ __forceinline__ float b2f(unsigned short u) {
    return __uint_as_float(((unsigned int)u) << 16);
}

// ---------------------------------------------------------------------------
// Fused input pack: one launch produces
//   xs   : NCHW u32 {lo=bf16(x), hi=bf16(share)}   (deform source)
//   sc16 : share in c16 layout [((b*4+cg)*HWC+pix)*16+ci]  (conv B)
//   oc16 : offset_feat in c16 layout                       (conv B)
// ---------------------------------------------------------------------------
__global__ __launch_bounds__(256) void pack_inputs_kernel(
    const float* __restrict__ x, const float* __restrict__ share,
    const float* __restrict__ offf,
    unsigned int* __restrict__ xs, unsigned short* __restrict__ sc16,
    unsigned short* __restrict__ oc16)
{
    __shared__ unsigned short lds[64][66];
    const int b = blockIdx.y;
    const int pix0 = blockIdx.x * 64;
    const int t = threadIdx.x;
    const int p = t & 63, q = t >> 6;
    const int pl = t & 63, cg = t >> 6;

    // Phase 1: share -> lds + xs write (share & x elementwise)
#pragma unroll
    for (int i = 0; i < 16; i++) {
        int c = i * 4 + q;
        size_t idx = ((size_t)b * 64 + c) * HWC + pix0 + p;
        unsigned short sb = bf16_rn(share[idx]);
        lds[c][p] = sb;
        xs[idx] = (unsigned int)bf16_rn(x[idx]) | ((unsigned int)sb << 16);
    }
    __syncthreads();
    {
        unsigned int u[8];
#pragma unroll
        for (int j = 0; j < 8; j++) {
            unsigned int lo = lds[cg * 16 + 2 * j][pl];
            unsigned int hi = lds[cg * 16 + 2 * j + 1][pl];
            u[j] = lo | (hi << 16);
        }
        unsigned int* dst = (unsigned int*)(sc16 + ((size_t)(b * 4 + cg) * HWC + pix0 + pl) * 16);
        *(uint4*)dst = make_uint4(u[0], u[1], u[2], u[3]);
        *(uint4*)(dst + 4) = make_uint4(u[4], u[5], u[6], u[7]);
    }
    __syncthreads();

    // Phase 2: offset_feat -> lds -> oc16
#pragma unroll
    for (int i = 0; i < 16; i++) {
        int c = i * 4 + q;
        lds[c][p] = bf16_rn(offf[((size_t)b * 64 + c) * HWC + pix0 + p]);
    }
    __syncthreads();
    {
        unsigned int u[8];
#pragma unroll
        for (int j = 0; j < 8; j++) {
            unsigned int lo = lds[cg * 16 + 2 * j][pl];
            unsigned int hi = lds[cg * 16 + 2 * j + 1][pl];
            u[j] = lo | (hi << 16);
        }
        unsigned int* dst = (unsigned int*)(oc16 + ((size_t)(b * 4 + cg) * HWC + pix0 + pl) * 16);
        *(uint4*)dst = make_uint4(u[0], u[1], u[2], u[3]);
        *(uint4*)(dst + 4) = make_uint4(u[4], u[5], u[6], u[7]);
    }
}

// ---------------------------------------------------------------------------
// All three conv weight packs in ONE launch.
// wp[((seg*9+kk)*4+cg)][co_pad][16c] bf16, zero-padded for co >= Cout.
// ---------------------------------------------------------------------------
__device__ __forceinline__ void pack_w_one(const float* __restrict__ w,
                                           unsigned short* __restrict__ wp,
                                           int Cout, int COP, int CinTot, int idx) {
    int i  = idx & 15;
    int co = (idx >> 4) % COP;
    int t  = idx / (16 * COP);       // t = (seg*9+kk)*4+cg
    int cg = t & 3;
    int kk = (t >> 2) % 9;
    int seg = t / 36;
    int cin = seg * 64 + cg * 16 + i;
    float v = (co < Cout) ? w[((size_t)co * CinTot + cin) * 9 + kk] : 0.f;
    wp[idx] = bf16_rn(v);
}

__global__ void pack_w_all_kernel(const float* __restrict__ w_om, unsigned short* __restrict__ wp_om,
                                  const float* __restrict__ w_em1, unsigned short* __restrict__ wp_em1,
                                  const float* __restrict__ w_em2, unsigned short* __restrict__ wp_em2) {
    int i = blockIdx.x * 256 + threadIdx.x;
    if (i < 129024) {
        pack_w_one(w_om, wp_om, 216, 224, 64, i);
    } else if (i < 129024 + 73728) {
        pack_w_one(w_em1, wp_em1, 64, 64, 128, i - 129024);
    } else if (i < 129024 + 73728 + 55296) {
        pack_w_one(w_em2, wp_em2, 72, 96, 64, i - 129024 - 73728);
    }
}

// ---------------------------------------------------------------------------
// Implicit-GEMM 3x3 conv via mfma_f32_32x32x16_bf16, inputs in c16 layout.
// Wave tile: 32 Cout x NT*32 px. Block = 4 waves = 4 rows. grid.x =
// B*(H/4)*XS, grid.y = COP/32. Straight-line K-loop: invalid rows handled by
// clamping the row and zeroing the A-fragment (conv zero-padding), so all
// loads are unconditional and the compiler can pipeline across kk steps.
// No min-waves clause (R4/R5: (256,4)/(256,2) caps forced massive spills).
// ---------------------------------------------------------------------------
template<int NSEG, int NT>
__global__ __launch_bounds__(256) void conv_mfma_kernel(
    const unsigned short* __restrict__ in0,
    const unsigned short* __restrict__ in1,
    const unsigned short* __restrict__ wp,
    const float* __restrict__ bias,
    void* __restrict__ out,
    int Cout, int COP, int out_mode, int act)
{
    constexpr int XS = 128 / (NT * 32);
    const int lane = threadIdx.x & 63;
    const int wid  = threadIdx.x >> 6;
    const int l31  = lane & 31;
    const int half = lane >> 5;
    int tmp = blockIdx.x;
    const int xsp = tmp % XS; tmp /= XS;
    const int rb  = tmp % (HH / 4);
    const int b   = tmp / (HH / 4);
    const int r   = rb * 4 + wid;          // image row, wave-uniform
    const int px0 = xsp * NT * 32;
    const int co0 = blockIdx.y * 32;

    f32x16 acc[NT];
#pragma unroll
    for (int nt = 0; nt < NT; nt++)
#pragma unroll
        for (int rg = 0; rg < 16; rg++) acc[nt][rg] = 0.f;

    bf16x8 bz;
#pragma unroll
    for (int i = 0; i < 8; i++) bz[i] = (__bf16)0.f;

#pragma unroll
    for (int seg = 0; seg < NSEG; seg++) {
        const unsigned short* in = seg ? in1 : in0;
        const unsigned short* inb = in + (size_t)b * 4 * HWC * 16;
#pragma unroll
        for (int kk = 0; kk < 9; kk++) {
            const int rr = r + kk / 3 - 1;
            const bool rv = (unsigned)rr < (unsigned)HH;
            const int rrc = min(max(rr, 0), HH - 1);
            const int dxo = kk % 3 - 1;
#pragma unroll
            for (int cg = 0; cg < 4; cg++) {
                bf16x8 afrag = *(const bf16x8*)(wp +
                    ((size_t)(((seg * 9 + kk) * 4 + cg) * COP + co0 + l31) * 16 + half * 8));
                if (!rv) afrag = bz;
                const size_t plane = ((size_t)cg * HWC + (size_t)rrc * WW) * 16;
#pragma unroll
                for (int nt = 0; nt < NT; nt++) {
                    const int cc = px0 + nt * 32 + l31 + dxo;
                    bf16x8 bfrag = bz;
                    if ((unsigned)cc < (unsigned)WW)
                        bfrag = *(const bf16x8*)(inb + plane + (size_t)cc * 16 + half * 8);
                    acc[nt] = __builtin_amdgcn_mfma_f32_32x32x16_bf16(afrag, bfrag, acc[nt], 0, 0, 0);
                }
            }
        }
    }

    // Epilogue: D layout col(pix)=lane&31, row(co)=(rg&3)+8*(rg>>2)+4*half
#pragma unroll
    for (int nt = 0; nt < NT; nt++) {
#pragma unroll
        for (int rg = 0; rg < 16; rg++) {
            const int row = (rg & 3) + 8 * (rg >> 2) + 4 * half;
            const int co = co0 + row;
            if (co < Cout) {
                float v = acc[nt][rg] + bias[co];
                if (act == 1)      v = (v >= 0.f) ? v : 0.1f * v;
                else if (act == 2) v = 1.f / (1.f + __expf(-v));
                else if (act == 3 && co >= 144) v = 1.f / (1.f + __expf(-v));
                const int pix = r * WW + px0 + nt * 32 + l31;
                if (out_mode == 2)
                    ((unsigned short*)out)[((size_t)b * Cout + co) * HWC + pix] = bf16_rn(v);
                else // c16
                    ((unsigned short*)out)[((size_t)(b * 4 + (co >> 4)) * HWC + pix) * 16 + (co & 15)] = bf16_rn(v);
            }
        }
    }
}

// ---------------------------------------------------------------------------
// Fused dual modulated deformable conv (unchanged from R6 working version).
// ---------------------------------------------------------------------------
__global__ __launch_bounds__(256) void deform_fused_kernel(
    const unsigned int* __restrict__ xs,
    const unsigned short* __restrict__ om, const unsigned short* __restrict__ em,
    const float* __restrict__ wdc, const float* __restrict__ bdc,
    float* __restrict__ outx, float* __restrict__ outs)
{
    __shared__ __align__(16) unsigned int lds[24 * DROW * DPAD];   // 29952 B

    const int bg = blockIdx.x >> 6;           // b*8+g
    const int b = bg >> 3, g = bg & 7;
    const int tile = blockIdx.x & 63;
    const int r0 = (tile >> 3) << 4;
    const int c0 = (tile & 7) << 4;
    const int tx = threadIdx.x & 15, ty = threadIdx.x >> 4;
    const int h = r0 + ty, w = c0 + tx;
    const int wr0 = r0 - 4, wc0 = c0 - 4;

    const unsigned int* xsb = xs + ((size_t)b * 64 + g * 8) * HWC;

#pragma unroll
    for (int i = 0; i < 18; i++) {
        unsigned int slot = (unsigned int)threadIdx.x + i * 256u;   // 0..4607
        unsigned int sx = slot % 24u;
        unsigned int t2 = slot / 24u;
        unsigned int sy = t2 % 24u;
        unsigned int c  = t2 / 24u;
        int iy = min(max(wr0 + (int)sy, 0), HH - 1);
        int ix = min(max(wc0 + (int)sx, 0), WW - 1);
        lds[(sy * DROW + sx) * DPAD + c] = xsb[(size_t)c * HWC + iy * WW + ix];
    }

    __syncthreads();

    const int pix = h * WW + w;
    const unsigned short* omb = om + (size_t)b * 216 * HWC + pix + (size_t)g * 18 * HWC;
    const unsigned short* mmb = om + (size_t)b * 216 * HWC + pix + (size_t)(144 + g * 9) * HWC;
    const unsigned short* emb = em + (size_t)b * 72 * HWC + pix + (size_t)g * 9 * HWC;

    float accx[8], accs[8];
#pragma unroll
    for (int o = 0; o < 8; o++) { accx[o] = 0.f; accs[o] = 0.f; }

#pragma unroll
    for (int kk = 0; kk < 9; kk++) {
        const float dy = b2f(omb[(size_t)(kk * 2) * HWC]);
        const float dx = b2f(omb[(size_t)(kk * 2 + 1) * HWC]);
        const float m1 = b2f(mmb[(size_t)kk * HWC]);
        const float m2 = b2f(emb[(size_t)kk * HWC]);

        const float py = (float)(h - 1 + kk / 3) + dy;
        const float px = (float)(w - 1 + kk % 3) + dx;
        const float y0f = floorf(py), x0f = floorf(px);
        const float ly = py - y0f, lx = px - x0f;
        const int y0 = (int)y0f, x0 = (int)x0f;
        const int y1 = y0 + 1, x1 = x0 + 1;
        const bool vy0 = (y0 >= 0) && (y0 < HH), vy1 = (y1 >= 0) && (y1 < HH);
        const bool vx0 = (x0 >= 0) && (x0 < WW), vx1 = (x1 >= 0) && (x1 < WW);
        float w00 = (1.f - ly) * (1.f - lx); if (!(vy0 && vx0)) w00 = 0.f;
        float w01 = (1.f - ly) * lx;         if (!(vy0 && vx1)) w01 = 0.f;
        float w10 = ly * (1.f - lx);         if (!(vy1 && vx0)) w10 = 0.f;
        float w11 = ly * lx;                 if (!(vy1 && vx1)) w11 = 0.f;
        const int cy0 = min(max(y0, 0), HH - 1), cy1 = min(max(y1, 0), HH - 1);
        const int cx0 = min(max(x0, 0), WW - 1), cx1 = min(max(x1, 0), WW - 1);

        const int sy0 = cy0 - wr0, sy1 = cy1 - wr0;
        const int sx0 = cx0 - wc0, sx1 = cx1 - wc0;
        const bool inw = (sy0 >= 0) && (sy1 < 24) && (sx0 >= 0) && (sx1 < 24);

        const float* wk = wdc + (size_t)g * 8 * 8 * 9 + kk;   // wk[(o*8+c)*9]

        if (__builtin_expect(inw, 1)) {
            const int p00 = (sy0 * DROW + sx0) * DPAD, p01 = (sy0 * DROW + sx1) * DPAD;
            const int p10 = (sy1 * DROW + sx0) * DPAD, p11 = (sy1 * DROW + sx1) * DPAD;
#pragma unroll
            for (int ch = 0; ch < 2; ch++) {
                uint4 qa = *(const uint4*)(lds + p00 + ch * 4);
                uint4 qb = *(const uint4*)(lds + p01 + ch * 4);
                uint4 qc = *(const uint4*)(lds + p10 + ch * 4);
                uint4 qd = *(const uint4*)(lds + p11 + ch * 4);
                const unsigned int ua[4] = {qa.x, qa.y, qa.z, qa.w};
                const unsigned int ub[4] = {qb.x, qb.y, qb.z, qb.w};
                const unsigned int uc[4] = {qc.x, qc.y, qc.z, qc.w};
                const unsigned int ud[4] = {qd.x, qd.y, qd.z, qd.w};
#pragma unroll
                for (int j = 0; j < 4; j++) {
                    const int c = ch * 4 + j;
                    float x00 = __uint_as_float(ua[j] << 16), s00 = __uint_as_float(ua[j] & 0xffff0000u);
                    float x01 = __uint_as_float(ub[j] << 16), s01 = __uint_as_float(ub[j] & 0xffff0000u);
                    float x10 = __uint_as_float(uc[j] << 16), s10 = __uint_as_float(uc[j] & 0xffff0000u);
                    float x11 = __uint_as_float(ud[j] << 16), s11 = __uint_as_float(ud[j] & 0xffff0000u);
                    float vx = w00 * x00; vx = fmaf(w01, x01, vx); vx = fmaf(w10, x10, vx); vx = fmaf(w11, x11, vx);
                    float vs = w00 * s00; vs = fmaf(w01, s01, vs); vs = fmaf(w10, s10, vs); vs = fmaf(w11, s11, vs);
                    vx *= m1;
                    vs *= m2;
#pragma unroll
                    for (int o = 0; o < 8; o++) {
                        const float wv = wk[(size_t)(o * 8 + c) * 9];
                        accx[o] = fmaf(vx, wv, accx[o]);
                        accs[o] = fmaf(vs, wv, accs[o]);
                    }
                }
            }
        } else {
            const int i00 = cy0 * WW + cx0, i01 = cy0 * WW + cx1;
            const int i10 = cy1 * WW + cx0, i11 = cy1 * WW + cx1;
#pragma unroll
            for (int c = 0; c < 8; c++) {
                const unsigned int* xc = xsb + (size_t)c * HWC;
                unsigned int a = xc[i00], bq = xc[i01], cq = xc[i10], dq = xc[i11];
                float x00 = __uint_as_float(a << 16),  s00 = __uint_as_float(a & 0xffff0000u);
                float x01 = __uint_as_float(bq << 16), s01 = __uint_as_float(bq & 0xffff0000u);
                float x10 = __uint_as_float(cq << 16), s10 = __uint_as_float(cq & 0xffff0000u);
                float x11 = __uint_as_float(dq << 16), s11 = __uint_as_float(dq & 0xffff0000u);
                float vx = w00 * x00; vx = fmaf(w01, x01, vx); vx = fmaf(w10, x10, vx); vx = fmaf(w11, x11, vx);
                float vs = w00 * s00; vs = fmaf(w01, s01, vs); vs = fmaf(w10, s10, vs); vs = fmaf(w11, s11, vs);
                vx *= m1;
                vs *= m2;
#pragma unroll
                for (int o = 0; o < 8; o++) {
                    const float wv = wk[(size_t)(o * 8 + c) * 9];
                    accx[o] = fmaf(vx, wv, accx[o]);
                    accs[o] = fmaf(vs, wv, accs[o]);
                }
            }
        }
    }

#pragma unroll
    for (int o = 0; o < 8; o++) {
        const float bv = bdc[g * 8 + o];
        outx[((size_t)(b * COO + g * 8 + o)) * HWC + pix] = accx[o] + bv;
        outs[((size_t)(b * COO + g * 8 + o)) * HWC + pix] = accs[o] + bv;
    }
}

// ---------------------------------------------------------------------------
extern "C" void kernel_launch(void* const* d_in, const int* in_sizes, int n_in,
                              void* d_out, int out_size, void* d_ws, size_t ws_size,
                              hipStream_t stream) {
    const float* x      = (const float*)d_in[0];
    const float* share  = (const float*)d_in[1];
    const float* offf   = (const float*)d_in[2];
    const float* w_om   = (const float*)d_in[3];
    const float* b_om   = (const float*)d_in[4];
    const float* w_em1  = (const float*)d_in[5];
    const float* b_em1  = (const float*)d_in[6];
    const float* w_em2  = (const float*)d_in[7];
    const float* b_em2  = (const float*)d_in[8];
    const float* w_dc   = (const float*)d_in[9];
    const float* b_dc   = (const float*)d_in[10];

    // Workspace layout
    unsigned int* xs = (unsigned int*)d_ws;           // 4194304 u32
    unsigned short* us = (unsigned short*)(xs + 4194304);
    unsigned short* sc16   = us;                      // 4194304 ush (share c16)
    unsigned short* oc16   = sc16 + 4194304;          // 4194304 (offf c16)
    unsigned short* emm    = oc16 + 4194304;          // 4194304 (em_mid c16)
    unsigned short* om_b   = emm + 4194304;           // 14155776 (om NCHW bf16)
    unsigned short* em_b   = om_b + 14155776;         // 4718592 (em NCHW bf16)
    unsigned short* wp_om  = em_b + 4718592;          // 129024
    unsigned short* wp_em1 = wp_om + 129024;          // 73728
    unsigned short* wp_em2 = wp_em1 + 73728;          // 55296

    float* outx = (float*)d_out;
    float* outs = outx + 4194304;

    dim3 blk(256);

    // Fused input + weight packing (2 launches instead of 6)
    pack_inputs_kernel<<<dim3(HWC / 64, BB), blk, 0, stream>>>(x, share, offf, xs, sc16, oc16);
    pack_w_all_kernel<<<(258048 + 255) / 256, blk, 0, stream>>>(
        w_om, wp_om, w_em1, wp_em1, w_em2, wp_em2);

    // om = conv(offset_feat) 64->216, sigmoid on mask channels, NCHW bf16
    conv_mfma_kernel<1, 2><<<dim3(BB * (HH / 4) * 2, 7), blk, 0, stream>>>(
        oc16, nullptr, wp_om, b_om, om_b, 216, 224, 2, 3);
    // em_mid = leaky(conv(concat(share, offf))) 128->64, c16 bf16
    conv_mfma_kernel<2, 1><<<dim3(BB * (HH / 4) * 4, 2), blk, 0, stream>>>(
        sc16, oc16, wp_em1, b_em1, emm, 64, 64, 3, 1);
    // em = sigmoid(conv(em_mid)) 64->72, NCHW bf16
    conv_mfma_kernel<1, 1><<<dim3(BB * (HH / 4) * 4, 3), blk, 0, stream>>>(
        emm, nullptr, wp_em2, b_em2, em_b, 72, 96, 2, 2);

    // fused dual deformable conv (LDS-staged gathers)
    deform_fused_kernel<<<dim3(BB * GG * 64), blk, 0, stream>>>(
        xs, om_b, em_b, w_dc, b_dc, outx, outs);
}